// Round 9
// baseline (448.254 us; speedup 1.0000x reference)
//
#include <hip/hip_runtime.h>
#include <hip/hip_bf16.h>
#include <hip/hip_fp16.h>

// GraphSAGE(2-layer, mean agg) + 3-layer MLP link predictor.
// N=100000, E=1.6M, E_PAIR=100000, D=128.
// Round 9: 3-phase CSR build — pre-partition edges by XCD region (compacted
// int2 list), then count/scatter stream only their own region's ~1.6MB slice,
// keeping the region's csr/cursor hot-set L2-resident. Weight cvts fused.

#define D 128
#define SCAN_B 512
#define LDA 40       // f16 elems per staged row (80B stride: 2-way banks = free)
#define LDC 264      // s_cat row stride f16 (528B: 2-way banks = free)
#define PART_CHUNK 4096

typedef _Float16 f16x8 __attribute__((ext_vector_type(8)));
typedef float f32x4 __attribute__((ext_vector_type(4)));

// ---------------- phase 1: region histogram + base scan ----------------
__global__ __launch_bounds__(256) void k_regcount(
    const int* __restrict__ dst, int* __restrict__ region_cnt, int e, int n) {
    __shared__ int s[8];
    if (threadIdx.x < 8) s[threadIdx.x] = 0;
    __syncthreads();
    int bound = (n + 7) / 8;
    for (int i = blockIdx.x * 256 + threadIdx.x; i < e; i += gridDim.x * 256)
        atomicAdd(&s[dst[i] / bound], 1);
    __syncthreads();
    if (threadIdx.x < 8) atomicAdd(&region_cnt[threadIdx.x], s[threadIdx.x]);
}

__global__ void k_regbase(const int* __restrict__ region_cnt,
                          int* __restrict__ region_base, int* __restrict__ region_cursor) {
    if (threadIdx.x == 0 && blockIdx.x == 0) {
        int run = 0;
        for (int r = 0; r < 8; ++r) {
            region_base[r] = run; region_cursor[r] = run; run += region_cnt[r];
        }
        region_base[8] = run;
    }
}

// ---------------- phase 2: partition edges into region-compacted int2 list ----------------
__global__ __launch_bounds__(256) void k_regpart(
    const int* __restrict__ src, const int* __restrict__ dst,
    int2* __restrict__ eout, int* __restrict__ region_cursor, int e, int n) {
    __shared__ int s_cnt[8];
    __shared__ int s_base[8];
    int bound = (n + 7) / 8;
    for (int c0 = blockIdx.x * PART_CHUNK; c0 < e; c0 += gridDim.x * PART_CHUNK) {
        int cend = min(c0 + PART_CHUNK, e);
        if (threadIdx.x < 8) s_cnt[threadIdx.x] = 0;
        __syncthreads();
        for (int i = c0 + threadIdx.x; i < cend; i += 256)
            atomicAdd(&s_cnt[dst[i] / bound], 1);
        __syncthreads();
        if (threadIdx.x < 8)
            s_base[threadIdx.x] = atomicAdd(&region_cursor[threadIdx.x], s_cnt[threadIdx.x]);
        __syncthreads();
        if (threadIdx.x < 8) s_cnt[threadIdx.x] = 0;
        __syncthreads();
        for (int i = c0 + threadIdx.x; i < cend; i += 256) {
            int d = dst[i];
            int r = d / bound;
            int p = atomicAdd(&s_cnt[r], 1);
            eout[s_base[r] + p] = make_int2(src[i], d);
        }
        __syncthreads();
    }
}

// ---------------- phase 3: count + scatter over region-local slices ----------------
__global__ __launch_bounds__(256) void k_count_deg2(
    const int2* __restrict__ ep, const int* __restrict__ region_base, int* __restrict__ cnt) {
    int region = blockIdx.x & 7;
    int slice = blockIdx.x >> 3;
    int nslice = gridDim.x >> 3;
    int beg = region_base[region], end = region_base[region + 1];
    int per = (end - beg + nslice - 1) / nslice;
    int s0 = beg + slice * per, s1 = min(s0 + per, end);
    for (int i = s0 + threadIdx.x; i < s1; i += 256)
        atomicAdd(&cnt[ep[i].y], 1);
}

__global__ __launch_bounds__(256) void k_scatter2(
    const int2* __restrict__ ep, const int* __restrict__ region_base,
    const int* __restrict__ row_off, int* __restrict__ cursor, int* __restrict__ csr) {
    int region = blockIdx.x & 7;
    int slice = blockIdx.x >> 3;
    int nslice = gridDim.x >> 3;
    int beg = region_base[region], end = region_base[region + 1];
    int per = (end - beg + nslice - 1) / nslice;
    int s0 = beg + slice * per, s1 = min(s0 + per, end);
    for (int i = s0 + threadIdx.x; i < s1; i += 256) {
        int2 sd = ep[i];
        int p = atomicAdd(&cursor[sd.y], 1);
        csr[row_off[sd.y] + p] = sd.x;
    }
}

__global__ void k_scan_block(const int* __restrict__ deg, int* __restrict__ row_off,
                             int* __restrict__ bsums, int n) {
    __shared__ int s[SCAN_B];
    int i = blockIdx.x * SCAN_B + threadIdx.x;
    int v = (i < n) ? deg[i] : 0;
    s[threadIdx.x] = v;
    __syncthreads();
    for (int off = 1; off < SCAN_B; off <<= 1) {
        int add = (threadIdx.x >= off) ? s[threadIdx.x - off] : 0;
        __syncthreads();
        s[threadIdx.x] += add;
        __syncthreads();
    }
    if (i < n) row_off[i + 1] = s[threadIdx.x];
    if (threadIdx.x == SCAN_B - 1) bsums[blockIdx.x] = s[threadIdx.x];
}

__global__ void k_scan_sums(int* __restrict__ bsums, int nb) {
    if (blockIdx.x == 0 && threadIdx.x == 0) {
        int run = 0;
        for (int b = 0; b < nb; ++b) { int t = bsums[b]; bsums[b] = run; run += t; }
    }
}

__global__ void k_scan_add(int* __restrict__ row_off, const int* __restrict__ bsums, int n) {
    int i = blockIdx.x * SCAN_B + threadIdx.x;
    if (i < n) row_off[i + 1] += bsums[blockIdx.x];
    if (i == 0) row_off[0] = 0;
}

// ---------------- f32 -> f16 converts ----------------
__global__ void k_cvt_f16(const float* __restrict__ src, _Float16* __restrict__ dst, int n8) {
    int i = blockIdx.x * 256 + threadIdx.x;
    if (i >= n8) return;
    const float4* s4 = (const float4*)src;
    float4 a = s4[2 * i], b = s4[2 * i + 1];
    f16x8 h;
    h[0] = (_Float16)a.x; h[1] = (_Float16)a.y; h[2] = (_Float16)a.z; h[3] = (_Float16)a.w;
    h[4] = (_Float16)b.x; h[5] = (_Float16)b.y; h[6] = (_Float16)b.z; h[7] = (_Float16)b.w;
    *(f16x8*)(dst + 8 * i) = h;
}

// all six weight matrices in one launch (grid = 14336 threads / 256 = 56 blocks)
__global__ void k_cvt_weights(
    const float* __restrict__ W1s, const float* __restrict__ W1n,
    const float* __restrict__ W2s, const float* __restrict__ W2n,
    const float* __restrict__ P1w, const float* __restrict__ P2w,
    _Float16* __restrict__ Ws1f, _Float16* __restrict__ Wn1f,
    _Float16* __restrict__ Ws2f, _Float16* __restrict__ Wn2f,
    _Float16* __restrict__ P1wf, _Float16* __restrict__ P2wf) {
    int g = blockIdx.x * 256 + threadIdx.x;
    const float* src; _Float16* dst; int off;
    if      (g <  2048) { src = W1s; dst = Ws1f; off = g; }
    else if (g <  4096) { src = W1n; dst = Wn1f; off = g - 2048; }
    else if (g <  6144) { src = W2s; dst = Ws2f; off = g - 4096; }
    else if (g <  8192) { src = W2n; dst = Wn2f; off = g - 6144; }
    else if (g < 12288) { src = P1w; dst = P1wf; off = g - 8192; }
    else if (g < 14336) { src = P2w; dst = P2wf; off = g - 12288; }
    else return;
    const float4* s4 = (const float4*)src;
    float4 a = s4[2 * off], b = s4[2 * off + 1];
    f16x8 h;
    h[0] = (_Float16)a.x; h[1] = (_Float16)a.y; h[2] = (_Float16)a.z; h[3] = (_Float16)a.w;
    h[4] = (_Float16)b.x; h[5] = (_Float16)b.y; h[6] = (_Float16)b.z; h[7] = (_Float16)b.w;
    *(f16x8*)(dst + 8 * off) = h;
}

// ---------------- mean aggregation: 16-lane group per node, 4-deep ----------------
__global__ __launch_bounds__(256) void k_agg(
    const _Float16* __restrict__ Xf, const int* __restrict__ row_off,
    const int* __restrict__ csr, _Float16* __restrict__ Aggf, int n_nodes) {
    int g = blockIdx.x * 16 + (threadIdx.x >> 4);
    if (g >= n_nodes) return;
    int l = threadIdx.x & 15;
    int beg = row_off[g], end = row_off[g + 1];
    float acc[8] = {0.f, 0.f, 0.f, 0.f, 0.f, 0.f, 0.f, 0.f};
    int i = beg;
    for (; i + 4 <= end; i += 4) {
        int s0 = csr[i], s1 = csr[i + 1], s2 = csr[i + 2], s3 = csr[i + 3];
        f16x8 v0 = *(const f16x8*)(Xf + (size_t)s0 * D + l * 8);
        f16x8 v1 = *(const f16x8*)(Xf + (size_t)s1 * D + l * 8);
        f16x8 v2 = *(const f16x8*)(Xf + (size_t)s2 * D + l * 8);
        f16x8 v3 = *(const f16x8*)(Xf + (size_t)s3 * D + l * 8);
        #pragma unroll
        for (int j = 0; j < 8; ++j)
            acc[j] += ((float)v0[j] + (float)v1[j]) + ((float)v2[j] + (float)v3[j]);
    }
    for (; i < end; ++i) {
        int s0 = csr[i];
        f16x8 v0 = *(const f16x8*)(Xf + (size_t)s0 * D + l * 8);
        #pragma unroll
        for (int j = 0; j < 8; ++j) acc[j] += (float)v0[j];
    }
    float inv = 1.0f / fmaxf((float)(end - beg), 1.0f);
    f16x8 o;
    #pragma unroll
    for (int j = 0; j < 8; ++j) o[j] = (_Float16)(acc[j] * inv);
    *(f16x8*)(Aggf + (size_t)g * D + l * 8) = o;
}

// ---------------- layer transform (MFMA, double-buffered) ----------------
__global__ __launch_bounds__(512) void k_transform(
    const _Float16* __restrict__ Xf, const _Float16* __restrict__ Aggf,
    const _Float16* __restrict__ Wsf, const _Float16* __restrict__ Wnf,
    const float* __restrict__ bias, _Float16* __restrict__ outf,
    int n_rows, int do_relu) {
    __shared__ _Float16 s_a[2][128 * LDA];
    __shared__ _Float16 s_b[2][128 * LDA];
    int tid = threadIdx.x;
    int w = tid >> 6, l = tid & 63;
    int wr = w >> 1, wc = w & 1;
    int l15 = l & 15, lk = l >> 4;
    int n0 = blockIdx.x * 128;
    int r = tid >> 2, q = tid & 3;
    int rstage = n0 + r; if (rstage >= n_rows) rstage = n_rows - 1;

    f32x4 acc[2][4];
    #pragma unroll
    for (int i = 0; i < 2; ++i)
        #pragma unroll
        for (int j = 0; j < 4; ++j) acc[i][j] = (f32x4){0.f, 0.f, 0.f, 0.f};

    int a_off = (wr * 32 + l15) * LDA + lk * 8;
    int b_off = (wc * 64 + l15) * LDA + lk * 8;
    int st_off = r * LDA + q * 8;

    {
        f16x8 av = *(const f16x8*)(Xf + (size_t)rstage * D + q * 8);
        f16x8 wv = *(const f16x8*)(Wsf + (size_t)r * D + q * 8);
        *(f16x8*)(&s_a[0][st_off]) = av;
        *(f16x8*)(&s_b[0][st_off]) = wv;
    }
    __syncthreads();

    for (int c = 0; c < 8; ++c) {
        int b = c & 1;
        f16x8 av, wv;
        if (c < 7) {
            int cn = c + 1;
            const _Float16* asrc = (cn < 4) ? Xf : Aggf;
            const _Float16* wsrc = (cn < 4) ? Wsf : Wnf;
            int kb = (cn & 3) * 32;
            av = *(const f16x8*)(asrc + (size_t)rstage * D + kb + q * 8);
            wv = *(const f16x8*)(wsrc + (size_t)r * D + kb + q * 8);
        }
        f16x8 af[2], bf[4];
        af[0] = *(const f16x8*)(&s_a[b][a_off]);
        af[1] = *(const f16x8*)(&s_a[b][a_off + 16 * LDA]);
        #pragma unroll
        for (int j = 0; j < 4; ++j) bf[j] = *(const f16x8*)(&s_b[b][b_off + j * 16 * LDA]);
        #pragma unroll
        for (int i = 0; i < 2; ++i)
            #pragma unroll
            for (int j = 0; j < 4; ++j)
                acc[i][j] = __builtin_amdgcn_mfma_f32_16x16x32_f16(af[i], bf[j], acc[i][j], 0, 0, 0);
        if (c < 7) {
            *(f16x8*)(&s_a[b ^ 1][st_off]) = av;
            *(f16x8*)(&s_b[b ^ 1][st_off]) = wv;
        }
        __syncthreads();
    }

    #pragma unroll
    for (int j = 0; j < 4; ++j) {
        int col = wc * 64 + j * 16 + l15;
        float bv = bias[col];
        #pragma unroll
        for (int i = 0; i < 2; ++i) {
            int rowb = n0 + wr * 32 + i * 16 + lk * 4;
            #pragma unroll
            for (int v = 0; v < 4; ++v) {
                int row = rowb + v;
                if (row < n_rows) {
                    float xv = acc[i][j][v] + bv;
                    if (do_relu) xv = fmaxf(xv, 0.f);
                    outf[(size_t)row * D + col] = (_Float16)xv;
                }
            }
        }
    }
}

// ---------------- fused predictor: gather-once, dbl-buffered weights ----------------
__global__ __launch_bounds__(256) void k_mlp(
    const _Float16* __restrict__ Hf,
    const int* __restrict__ pos_src, const int* __restrict__ pos_dst,
    const int* __restrict__ neg_src, const int* __restrict__ neg_dst,
    const _Float16* __restrict__ P1wf, const float* __restrict__ P1b,
    const _Float16* __restrict__ P2wf, const float* __restrict__ P2b,
    const float* __restrict__ P3w, const float* __restrict__ P3b,
    float* __restrict__ out, int EP) {
    __shared__ _Float16 s_cat[64 * LDC];
    __shared__ _Float16 s_b[2][128 * LDA];
    __shared__ float s_red[64 * 2];
    __shared__ int s_node[128];
    int tid = threadIdx.x;
    int w = tid >> 6, l = tid & 63;
    int wr = w >> 1, wc = w & 1;
    int l15 = l & 15, lk = l >> 4;
    int p0 = blockIdx.x * 64;
    int twoEP = 2 * EP;

    if (tid < 128) {
        int p = p0 + (tid & 63);
        if (p >= twoEP) p = twoEP - 1;
        int node;
        if (tid < 64) node = (p < EP) ? pos_src[p] : neg_src[p - EP];
        else          node = (p < EP) ? pos_dst[p] : neg_dst[p - EP];
        s_node[tid] = node;
    }
    __syncthreads();

    #pragma unroll
    for (int e = 0; e < 8; ++e) {
        int idx = tid + e * 256;
        int rr = idx >> 4, u = idx & 15;
        int node = s_node[rr];
        f16x8 v = *(const f16x8*)(Hf + (size_t)node * D + u * 8);
        *(f16x8*)(s_cat + (rr & 63) * LDC + (rr >> 6) * 128 + u * 8) = v;
    }
    #pragma unroll
    for (int e = 0; e < 2; ++e) {
        int idx = tid + e * 256;
        int o = idx >> 2, q = idx & 3;
        *(f16x8*)(&s_b[0][o * LDA + q * 8]) = *(const f16x8*)(P1wf + (size_t)o * 256 + q * 8);
    }
    __syncthreads();

    f32x4 acc[2][4];
    #pragma unroll
    for (int i = 0; i < 2; ++i)
        #pragma unroll
        for (int j = 0; j < 4; ++j) acc[i][j] = (f32x4){0.f, 0.f, 0.f, 0.f};

    for (int c = 0; c < 8; ++c) {
        int b = c & 1;
        f16x8 nw[2];
        if (c < 7) {
            #pragma unroll
            for (int e = 0; e < 2; ++e) {
                int idx = tid + e * 256;
                int o = idx >> 2, q = idx & 3;
                nw[e] = *(const f16x8*)(P1wf + (size_t)o * 256 + (c + 1) * 32 + q * 8);
            }
        }
        f16x8 af[2], bf[4];
        af[0] = *(const f16x8*)(s_cat + (wr * 32 + l15) * LDC + c * 32 + lk * 8);
        af[1] = *(const f16x8*)(s_cat + (wr * 32 + 16 + l15) * LDC + c * 32 + lk * 8);
        #pragma unroll
        for (int j = 0; j < 4; ++j)
            bf[j] = *(const f16x8*)(&s_b[b][(wc * 64 + j * 16 + l15) * LDA + lk * 8]);
        #pragma unroll
        for (int i = 0; i < 2; ++i)
            #pragma unroll
            for (int j = 0; j < 4; ++j)
                acc[i][j] = __builtin_amdgcn_mfma_f32_16x16x32_f16(af[i], bf[j], acc[i][j], 0, 0, 0);
        if (c < 7) {
            #pragma unroll
            for (int e = 0; e < 2; ++e) {
                int idx = tid + e * 256;
                int o = idx >> 2, q = idx & 3;
                *(f16x8*)(&s_b[b ^ 1][o * LDA + q * 8]) = nw[e];
            }
        }
        __syncthreads();
    }

    #pragma unroll
    for (int j = 0; j < 4; ++j) {
        int col = wc * 64 + j * 16 + l15;
        float bv = P1b[col];
        #pragma unroll
        for (int i = 0; i < 2; ++i) {
            int rowb = wr * 32 + i * 16 + lk * 4;
            #pragma unroll
            for (int v = 0; v < 4; ++v)
                s_cat[(rowb + v) * LDC + col] = (_Float16)fmaxf(acc[i][j][v] + bv, 0.f);
        }
    }
    #pragma unroll
    for (int e = 0; e < 2; ++e) {
        int idx = tid + e * 256;
        int o = idx >> 2, q = idx & 3;
        *(f16x8*)(&s_b[0][o * LDA + q * 8]) = *(const f16x8*)(P2wf + (size_t)o * D + q * 8);
    }
    __syncthreads();

    f32x4 acc2[2][4];
    #pragma unroll
    for (int i = 0; i < 2; ++i)
        #pragma unroll
        for (int j = 0; j < 4; ++j) acc2[i][j] = (f32x4){0.f, 0.f, 0.f, 0.f};

    for (int c = 0; c < 4; ++c) {
        int b = c & 1;
        f16x8 nw[2];
        if (c < 3) {
            #pragma unroll
            for (int e = 0; e < 2; ++e) {
                int idx = tid + e * 256;
                int o = idx >> 2, q = idx & 3;
                nw[e] = *(const f16x8*)(P2wf + (size_t)o * D + (c + 1) * 32 + q * 8);
            }
        }
        f16x8 af[2], bf[4];
        af[0] = *(const f16x8*)(s_cat + (wr * 32 + l15) * LDC + c * 32 + lk * 8);
        af[1] = *(const f16x8*)(s_cat + (wr * 32 + 16 + l15) * LDC + c * 32 + lk * 8);
        #pragma unroll
        for (int j = 0; j < 4; ++j)
            bf[j] = *(const f16x8*)(&s_b[b][(wc * 64 + j * 16 + l15) * LDA + lk * 8]);
        #pragma unroll
        for (int i = 0; i < 2; ++i)
            #pragma unroll
            for (int j = 0; j < 4; ++j)
                acc2[i][j] = __builtin_amdgcn_mfma_f32_16x16x32_f16(af[i], bf[j], acc2[i][j], 0, 0, 0);
        if (c < 3) {
            #pragma unroll
            for (int e = 0; e < 2; ++e) {
                int idx = tid + e * 256;
                int o = idx >> 2, q = idx & 3;
                *(f16x8*)(&s_b[b ^ 1][o * LDA + q * 8]) = nw[e];
            }
        }
        __syncthreads();
    }

    float b2v[4], pw[4];
    #pragma unroll
    for (int j = 0; j < 4; ++j) {
        int col = wc * 64 + j * 16 + l15;
        b2v[j] = P2b[col];
        pw[j] = P3w[col];
    }
    #pragma unroll
    for (int i = 0; i < 2; ++i) {
        #pragma unroll
        for (int v = 0; v < 4; ++v) {
            float s = 0.f;
            #pragma unroll
            for (int j = 0; j < 4; ++j)
                s += fmaxf(acc2[i][j][v] + b2v[j], 0.f) * pw[j];
            s += __shfl_xor(s, 1);
            s += __shfl_xor(s, 2);
            s += __shfl_xor(s, 4);
            s += __shfl_xor(s, 8);
            if (l15 == 0)
                s_red[(wr * 32 + i * 16 + lk * 4 + v) * 2 + wc] = s;
        }
    }
    __syncthreads();
    if (tid < 64) {
        int p = p0 + tid;
        if (p < twoEP) out[p] = s_red[tid * 2] + s_red[tid * 2 + 1] + P3b[0];
    }
}

static inline size_t align_up(size_t x, size_t a) { return (x + a - 1) & ~(a - 1); }

extern "C" void kernel_launch(void* const* d_in, const int* in_sizes, int n_in,
                              void* d_out, int out_size, void* d_ws, size_t ws_size,
                              hipStream_t stream) {
    const float* x        = (const float*)d_in[0];
    const int*   edge_src = (const int*)d_in[1];
    const int*   edge_dst = (const int*)d_in[2];
    const int*   pos_src  = (const int*)d_in[3];
    const int*   pos_dst  = (const int*)d_in[4];
    const int*   neg_src  = (const int*)d_in[5];
    const int*   neg_dst  = (const int*)d_in[6];
    const float* W1n = (const float*)d_in[7];
    const float* W1s = (const float*)d_in[8];
    const float* b1  = (const float*)d_in[9];
    const float* W2n = (const float*)d_in[10];
    const float* W2s = (const float*)d_in[11];
    const float* b2  = (const float*)d_in[12];
    const float* P1w = (const float*)d_in[13];
    const float* P1b = (const float*)d_in[14];
    const float* P2w = (const float*)d_in[15];
    const float* P2b = (const float*)d_in[16];
    const float* P3w = (const float*)d_in[17];
    const float* P3b = (const float*)d_in[18];
    float* out = (float*)d_out;

    const int N = in_sizes[0] / D;
    const int E = in_sizes[1];
    const int EP = in_sizes[3];

    char* ws = (char*)d_ws;
    size_t off = 0;
    int* row_off = (int*)(ws + off); off = align_up(off + (size_t)(N + 1) * 4, 256);
    int* cursor  = (int*)(ws + off); off = align_up(off + (size_t)N * 4, 256);
    int* bsums   = (int*)(ws + off); off = align_up(off + 4096, 256);
    int* regmeta = (int*)(ws + off); off = align_up(off + 32 * 4, 256);
    int* csr     = (int*)(ws + off); off = align_up(off + (size_t)E * 4, 256);
    int2* epart  = (int2*)(ws + off); off = align_up(off + (size_t)E * 8, 256);
    _Float16* xf   = (_Float16*)(ws + off); off = align_up(off + (size_t)N * D * 2, 256);
    _Float16* aggf = (_Float16*)(ws + off); off = align_up(off + (size_t)N * D * 2, 256);
    _Float16* h1f  = (_Float16*)(ws + off); off = align_up(off + (size_t)N * D * 2, 256);
    _Float16* h2f  = (_Float16*)(ws + off); off = align_up(off + (size_t)N * D * 2, 256);
    _Float16* Ws1f = (_Float16*)(ws + off); off = align_up(off + (size_t)D * D * 2, 256);
    _Float16* Wn1f = (_Float16*)(ws + off); off = align_up(off + (size_t)D * D * 2, 256);
    _Float16* Ws2f = (_Float16*)(ws + off); off = align_up(off + (size_t)D * D * 2, 256);
    _Float16* Wn2f = (_Float16*)(ws + off); off = align_up(off + (size_t)D * D * 2, 256);
    _Float16* P1wf = (_Float16*)(ws + off); off = align_up(off + (size_t)2 * D * D * 2, 256);
    _Float16* P2wf = (_Float16*)(ws + off); off = align_up(off + (size_t)D * D * 2, 256);
    (void)ws_size;

    int* region_cnt    = regmeta;        // [8]
    int* region_base   = regmeta + 8;    // [9]
    int* region_cursor = regmeta + 20;   // [8]

    const int nb_scan = (N + SCAN_B - 1) / SCAN_B;
    const int GR2 = 512;   // 8 regions x 64 slices

    // --- CSR build: partition, count, scan, scatter ---
    hipMemsetAsync(cursor, 0, (size_t)N * 4, stream);
    hipMemsetAsync(regmeta, 0, 32 * 4, stream);
    k_regcount<<<256, 256, 0, stream>>>(edge_dst, region_cnt, E, N);
    k_regbase<<<1, 1, 0, stream>>>(region_cnt, region_base, region_cursor);
    k_regpart<<<(E + PART_CHUNK - 1) / PART_CHUNK, 256, 0, stream>>>(
        edge_src, edge_dst, epart, region_cursor, E, N);
    k_count_deg2<<<GR2, 256, 0, stream>>>(epart, region_base, cursor);
    k_scan_block<<<nb_scan, SCAN_B, 0, stream>>>(cursor, row_off, bsums, N);
    k_scan_sums<<<1, 64, 0, stream>>>(bsums, nb_scan);
    k_scan_add<<<nb_scan, SCAN_B, 0, stream>>>(row_off, bsums, N);
    hipMemsetAsync(cursor, 0, (size_t)N * 4, stream);
    k_scatter2<<<GR2, 256, 0, stream>>>(epart, region_base, row_off, cursor, csr);

    // --- f16 conversions ---
    k_cvt_f16<<<(N * D / 8 + 255) / 256, 256, 0, stream>>>(x, xf, N * D / 8);
    k_cvt_weights<<<56, 256, 0, stream>>>(W1s, W1n, W2s, W2n, P1w, P2w,
                                          Ws1f, Wn1f, Ws2f, Wn2f, P1wf, P2wf);

    const int ngrid = (N + 127) / 128;
    const int pgrid = (2 * EP + 63) / 64;

    // --- layer 1 ---
    k_agg<<<(N + 15) / 16, 256, 0, stream>>>(xf, row_off, csr, aggf, N);
    k_transform<<<ngrid, 512, 0, stream>>>(xf, aggf, Ws1f, Wn1f, b1, h1f, N, 1);
    // --- layer 2 ---
    k_agg<<<(N + 15) / 16, 256, 0, stream>>>(h1f, row_off, csr, aggf, N);
    k_transform<<<ngrid, 512, 0, stream>>>(h1f, aggf, Ws2f, Wn2f, b2, h2f, N, 0);

    // --- fused predictor ---
    k_mlp<<<pgrid, 256, 0, stream>>>(h2f, pos_src, pos_dst, neg_src, neg_dst,
                                     P1wf, P1b, P2wf, P2b, P3w, P3b, out, EP);
}

// Round 10
// 326.376 us; speedup vs baseline: 1.3734x; 1.3734x over previous
//
#include <hip/hip_runtime.h>
#include <hip/hip_bf16.h>
#include <hip/hip_fp16.h>

// GraphSAGE(2-layer, mean agg) + 3-layer MLP link predictor.
// N=100000, E=1.6M, E_PAIR=100000, D=128.
// Round 10: atomic-free CSR build. NR=512 node-range regions; edges packed
// (src | doff<<20) and region-compacted; per-region blocks do LDS-atomic
// degree count + in-block scan (row_off written directly, no global scan)
// and LDS-cursor scatter. No device-scope atomics in the per-edge hot path.

#define D 128
#define NR 512
#define PART_CHUNK 4096
#define LDA 40       // f16 elems per staged row (80B stride: 2-way banks = free)
#define LDC 264      // s_cat row stride f16 (528B: 2-way banks = free)

typedef _Float16 f16x8 __attribute__((ext_vector_type(8)));
typedef float f32x4 __attribute__((ext_vector_type(4)));

// ---------------- phase 1: region histogram ----------------
__global__ __launch_bounds__(256) void k_regcount(
    const int* __restrict__ dst, int* __restrict__ region_cnt, int e, int bound) {
    __shared__ int s[NR];
    for (int i = threadIdx.x; i < NR; i += 256) s[i] = 0;
    __syncthreads();
    for (int i = blockIdx.x * 256 + threadIdx.x; i < e; i += gridDim.x * 256)
        atomicAdd(&s[dst[i] / bound], 1);
    __syncthreads();
    for (int i = threadIdx.x; i < NR; i += 256)
        if (s[i]) atomicAdd(&region_cnt[i], s[i]);
}

__global__ void k_regbase(const int* __restrict__ region_cnt,
                          int* __restrict__ region_base, int* __restrict__ region_cursor) {
    if (threadIdx.x == 0 && blockIdx.x == 0) {
        int run = 0;
        for (int r = 0; r < NR; ++r) {
            region_base[r] = run; region_cursor[r] = run; run += region_cnt[r];
        }
        region_base[NR] = run;
    }
}

// ---------------- phase 2: partition edges into region-compacted packed list ----------------
// packed edge: src | (doff << 20), doff = dst - region*bound (< 256)
__global__ __launch_bounds__(256) void k_regpart(
    const int* __restrict__ src, const int* __restrict__ dst,
    unsigned int* __restrict__ eout, int* __restrict__ region_cursor, int e, int bound) {
    __shared__ int s_cnt[NR];
    __shared__ int s_base[NR];
    for (int c0 = blockIdx.x * PART_CHUNK; c0 < e; c0 += gridDim.x * PART_CHUNK) {
        int cend = min(c0 + PART_CHUNK, e);
        for (int i = threadIdx.x; i < NR; i += 256) s_cnt[i] = 0;
        __syncthreads();
        for (int i = c0 + threadIdx.x; i < cend; i += 256)
            atomicAdd(&s_cnt[dst[i] / bound], 1);
        __syncthreads();
        for (int i = threadIdx.x; i < NR; i += 256)
            s_base[i] = s_cnt[i] ? atomicAdd(&region_cursor[i], s_cnt[i]) : 0;
        __syncthreads();
        for (int i = threadIdx.x; i < NR; i += 256) s_cnt[i] = 0;
        __syncthreads();
        for (int i = c0 + threadIdx.x; i < cend; i += 256) {
            int d = dst[i];
            int r = d / bound;
            unsigned int doff = (unsigned int)(d - r * bound);
            int p = atomicAdd(&s_cnt[r], 1);
            eout[s_base[r] + p] = (unsigned int)src[i] | (doff << 20);
        }
        __syncthreads();
    }
}

// ---------------- phase 3a: per-region degree count + scan -> row_off ----------------
__global__ __launch_bounds__(256) void k_rowoff(
    const unsigned int* __restrict__ ep, const int* __restrict__ region_base,
    int* __restrict__ row_off, int n, int bound) {
    int r = blockIdx.x;
    int rlo = r * bound;
    if (threadIdx.x == 0 && r == 0) row_off[n] = region_base[NR];
    if (rlo >= n) return;
    int nn = min(bound, n - rlo);
    __shared__ int s_deg[256];
    __shared__ int s_scan[256];
    if (threadIdx.x < 256) s_deg[threadIdx.x] = 0;
    __syncthreads();
    int beg = region_base[r], end = region_base[r + 1];
    for (int i = beg + threadIdx.x; i < end; i += 256)
        atomicAdd(&s_deg[ep[i] >> 20], 1);
    __syncthreads();
    int v = (threadIdx.x < nn) ? s_deg[threadIdx.x] : 0;
    s_scan[threadIdx.x] = v;
    __syncthreads();
    #pragma unroll
    for (int off = 1; off < 256; off <<= 1) {
        int add = (threadIdx.x >= off) ? s_scan[threadIdx.x - off] : 0;
        __syncthreads();
        s_scan[threadIdx.x] += add;
        __syncthreads();
    }
    if (threadIdx.x < nn)
        row_off[rlo + threadIdx.x] = region_base[r] +
            (threadIdx.x ? s_scan[threadIdx.x - 1] : 0);
}

// ---------------- phase 3b: per-region scatter with LDS cursor ----------------
__global__ __launch_bounds__(256) void k_scatter3(
    const unsigned int* __restrict__ ep, const int* __restrict__ region_base,
    const int* __restrict__ row_off, int* __restrict__ csr, int n, int bound) {
    int r = blockIdx.x;
    int rlo = r * bound;
    if (rlo >= n) return;
    int nn = min(bound, n - rlo);
    __shared__ int s_cur[256];
    __shared__ int s_ro[256];
    if (threadIdx.x < nn) {
        s_cur[threadIdx.x] = 0;
        s_ro[threadIdx.x] = row_off[rlo + threadIdx.x];
    }
    __syncthreads();
    int beg = region_base[r], end = region_base[r + 1];
    for (int i = beg + threadIdx.x; i < end; i += 256) {
        unsigned int v = ep[i];
        int doff = v >> 20;
        int srcn = v & 0xFFFFF;
        int p = atomicAdd(&s_cur[doff], 1);
        csr[s_ro[doff] + p] = srcn;
    }
}

// ---------------- f32 -> f16 converts ----------------
__global__ void k_cvt_f16(const float* __restrict__ src, _Float16* __restrict__ dst, int n8) {
    int i = blockIdx.x * 256 + threadIdx.x;
    if (i >= n8) return;
    const float4* s4 = (const float4*)src;
    float4 a = s4[2 * i], b = s4[2 * i + 1];
    f16x8 h;
    h[0] = (_Float16)a.x; h[1] = (_Float16)a.y; h[2] = (_Float16)a.z; h[3] = (_Float16)a.w;
    h[4] = (_Float16)b.x; h[5] = (_Float16)b.y; h[6] = (_Float16)b.z; h[7] = (_Float16)b.w;
    *(f16x8*)(dst + 8 * i) = h;
}

__global__ void k_cvt_weights(
    const float* __restrict__ W1s, const float* __restrict__ W1n,
    const float* __restrict__ W2s, const float* __restrict__ W2n,
    const float* __restrict__ P1w, const float* __restrict__ P2w,
    _Float16* __restrict__ Ws1f, _Float16* __restrict__ Wn1f,
    _Float16* __restrict__ Ws2f, _Float16* __restrict__ Wn2f,
    _Float16* __restrict__ P1wf, _Float16* __restrict__ P2wf) {
    int g = blockIdx.x * 256 + threadIdx.x;
    const float* src; _Float16* dst; int off;
    if      (g <  2048) { src = W1s; dst = Ws1f; off = g; }
    else if (g <  4096) { src = W1n; dst = Wn1f; off = g - 2048; }
    else if (g <  6144) { src = W2s; dst = Ws2f; off = g - 4096; }
    else if (g <  8192) { src = W2n; dst = Wn2f; off = g - 6144; }
    else if (g < 12288) { src = P1w; dst = P1wf; off = g - 8192; }
    else if (g < 14336) { src = P2w; dst = P2wf; off = g - 12288; }
    else return;
    const float4* s4 = (const float4*)src;
    float4 a = s4[2 * off], b = s4[2 * off + 1];
    f16x8 h;
    h[0] = (_Float16)a.x; h[1] = (_Float16)a.y; h[2] = (_Float16)a.z; h[3] = (_Float16)a.w;
    h[4] = (_Float16)b.x; h[5] = (_Float16)b.y; h[6] = (_Float16)b.z; h[7] = (_Float16)b.w;
    *(f16x8*)(dst + 8 * off) = h;
}

// ---------------- mean aggregation: 16-lane group per node, 4-deep ----------------
__global__ __launch_bounds__(256) void k_agg(
    const _Float16* __restrict__ Xf, const int* __restrict__ row_off,
    const int* __restrict__ csr, _Float16* __restrict__ Aggf, int n_nodes) {
    int g = blockIdx.x * 16 + (threadIdx.x >> 4);
    if (g >= n_nodes) return;
    int l = threadIdx.x & 15;
    int beg = row_off[g], end = row_off[g + 1];
    float acc[8] = {0.f, 0.f, 0.f, 0.f, 0.f, 0.f, 0.f, 0.f};
    int i = beg;
    for (; i + 4 <= end; i += 4) {
        int s0 = csr[i], s1 = csr[i + 1], s2 = csr[i + 2], s3 = csr[i + 3];
        f16x8 v0 = *(const f16x8*)(Xf + (size_t)s0 * D + l * 8);
        f16x8 v1 = *(const f16x8*)(Xf + (size_t)s1 * D + l * 8);
        f16x8 v2 = *(const f16x8*)(Xf + (size_t)s2 * D + l * 8);
        f16x8 v3 = *(const f16x8*)(Xf + (size_t)s3 * D + l * 8);
        #pragma unroll
        for (int j = 0; j < 8; ++j)
            acc[j] += ((float)v0[j] + (float)v1[j]) + ((float)v2[j] + (float)v3[j]);
    }
    for (; i < end; ++i) {
        int s0 = csr[i];
        f16x8 v0 = *(const f16x8*)(Xf + (size_t)s0 * D + l * 8);
        #pragma unroll
        for (int j = 0; j < 8; ++j) acc[j] += (float)v0[j];
    }
    float inv = 1.0f / fmaxf((float)(end - beg), 1.0f);
    f16x8 o;
    #pragma unroll
    for (int j = 0; j < 8; ++j) o[j] = (_Float16)(acc[j] * inv);
    *(f16x8*)(Aggf + (size_t)g * D + l * 8) = o;
}

// ---------------- layer transform (MFMA, double-buffered) ----------------
__global__ __launch_bounds__(512) void k_transform(
    const _Float16* __restrict__ Xf, const _Float16* __restrict__ Aggf,
    const _Float16* __restrict__ Wsf, const _Float16* __restrict__ Wnf,
    const float* __restrict__ bias, _Float16* __restrict__ outf,
    int n_rows, int do_relu) {
    __shared__ _Float16 s_a[2][128 * LDA];
    __shared__ _Float16 s_b[2][128 * LDA];
    int tid = threadIdx.x;
    int w = tid >> 6, l = tid & 63;
    int wr = w >> 1, wc = w & 1;
    int l15 = l & 15, lk = l >> 4;
    int n0 = blockIdx.x * 128;
    int r = tid >> 2, q = tid & 3;
    int rstage = n0 + r; if (rstage >= n_rows) rstage = n_rows - 1;

    f32x4 acc[2][4];
    #pragma unroll
    for (int i = 0; i < 2; ++i)
        #pragma unroll
        for (int j = 0; j < 4; ++j) acc[i][j] = (f32x4){0.f, 0.f, 0.f, 0.f};

    int a_off = (wr * 32 + l15) * LDA + lk * 8;
    int b_off = (wc * 64 + l15) * LDA + lk * 8;
    int st_off = r * LDA + q * 8;

    {
        f16x8 av = *(const f16x8*)(Xf + (size_t)rstage * D + q * 8);
        f16x8 wv = *(const f16x8*)(Wsf + (size_t)r * D + q * 8);
        *(f16x8*)(&s_a[0][st_off]) = av;
        *(f16x8*)(&s_b[0][st_off]) = wv;
    }
    __syncthreads();

    for (int c = 0; c < 8; ++c) {
        int b = c & 1;
        f16x8 av, wv;
        if (c < 7) {
            int cn = c + 1;
            const _Float16* asrc = (cn < 4) ? Xf : Aggf;
            const _Float16* wsrc = (cn < 4) ? Wsf : Wnf;
            int kb = (cn & 3) * 32;
            av = *(const f16x8*)(asrc + (size_t)rstage * D + kb + q * 8);
            wv = *(const f16x8*)(wsrc + (size_t)r * D + kb + q * 8);
        }
        f16x8 af[2], bf[4];
        af[0] = *(const f16x8*)(&s_a[b][a_off]);
        af[1] = *(const f16x8*)(&s_a[b][a_off + 16 * LDA]);
        #pragma unroll
        for (int j = 0; j < 4; ++j) bf[j] = *(const f16x8*)(&s_b[b][b_off + j * 16 * LDA]);
        #pragma unroll
        for (int i = 0; i < 2; ++i)
            #pragma unroll
            for (int j = 0; j < 4; ++j)
                acc[i][j] = __builtin_amdgcn_mfma_f32_16x16x32_f16(af[i], bf[j], acc[i][j], 0, 0, 0);
        if (c < 7) {
            *(f16x8*)(&s_a[b ^ 1][st_off]) = av;
            *(f16x8*)(&s_b[b ^ 1][st_off]) = wv;
        }
        __syncthreads();
    }

    #pragma unroll
    for (int j = 0; j < 4; ++j) {
        int col = wc * 64 + j * 16 + l15;
        float bv = bias[col];
        #pragma unroll
        for (int i = 0; i < 2; ++i) {
            int rowb = n0 + wr * 32 + i * 16 + lk * 4;
            #pragma unroll
            for (int v = 0; v < 4; ++v) {
                int row = rowb + v;
                if (row < n_rows) {
                    float xv = acc[i][j][v] + bv;
                    if (do_relu) xv = fmaxf(xv, 0.f);
                    outf[(size_t)row * D + col] = (_Float16)xv;
                }
            }
        }
    }
}

// ---------------- fused predictor: gather-once, dbl-buffered weights ----------------
__global__ __launch_bounds__(256) void k_mlp(
    const _Float16* __restrict__ Hf,
    const int* __restrict__ pos_src, const int* __restrict__ pos_dst,
    const int* __restrict__ neg_src, const int* __restrict__ neg_dst,
    const _Float16* __restrict__ P1wf, const float* __restrict__ P1b,
    const _Float16* __restrict__ P2wf, const float* __restrict__ P2b,
    const float* __restrict__ P3w, const float* __restrict__ P3b,
    float* __restrict__ out, int EP) {
    __shared__ _Float16 s_cat[64 * LDC];
    __shared__ _Float16 s_b[2][128 * LDA];
    __shared__ float s_red[64 * 2];
    __shared__ int s_node[128];
    int tid = threadIdx.x;
    int w = tid >> 6, l = tid & 63;
    int wr = w >> 1, wc = w & 1;
    int l15 = l & 15, lk = l >> 4;
    int p0 = blockIdx.x * 64;
    int twoEP = 2 * EP;

    if (tid < 128) {
        int p = p0 + (tid & 63);
        if (p >= twoEP) p = twoEP - 1;
        int node;
        if (tid < 64) node = (p < EP) ? pos_src[p] : neg_src[p - EP];
        else          node = (p < EP) ? pos_dst[p] : neg_dst[p - EP];
        s_node[tid] = node;
    }
    __syncthreads();

    #pragma unroll
    for (int e = 0; e < 8; ++e) {
        int idx = tid + e * 256;
        int rr = idx >> 4, u = idx & 15;
        int node = s_node[rr];
        f16x8 v = *(const f16x8*)(Hf + (size_t)node * D + u * 8);
        *(f16x8*)(s_cat + (rr & 63) * LDC + (rr >> 6) * 128 + u * 8) = v;
    }
    #pragma unroll
    for (int e = 0; e < 2; ++e) {
        int idx = tid + e * 256;
        int o = idx >> 2, q = idx & 3;
        *(f16x8*)(&s_b[0][o * LDA + q * 8]) = *(const f16x8*)(P1wf + (size_t)o * 256 + q * 8);
    }
    __syncthreads();

    f32x4 acc[2][4];
    #pragma unroll
    for (int i = 0; i < 2; ++i)
        #pragma unroll
        for (int j = 0; j < 4; ++j) acc[i][j] = (f32x4){0.f, 0.f, 0.f, 0.f};

    for (int c = 0; c < 8; ++c) {
        int b = c & 1;
        f16x8 nw[2];
        if (c < 7) {
            #pragma unroll
            for (int e = 0; e < 2; ++e) {
                int idx = tid + e * 256;
                int o = idx >> 2, q = idx & 3;
                nw[e] = *(const f16x8*)(P1wf + (size_t)o * 256 + (c + 1) * 32 + q * 8);
            }
        }
        f16x8 af[2], bf[4];
        af[0] = *(const f16x8*)(s_cat + (wr * 32 + l15) * LDC + c * 32 + lk * 8);
        af[1] = *(const f16x8*)(s_cat + (wr * 32 + 16 + l15) * LDC + c * 32 + lk * 8);
        #pragma unroll
        for (int j = 0; j < 4; ++j)
            bf[j] = *(const f16x8*)(&s_b[b][(wc * 64 + j * 16 + l15) * LDA + lk * 8]);
        #pragma unroll
        for (int i = 0; i < 2; ++i)
            #pragma unroll
            for (int j = 0; j < 4; ++j)
                acc[i][j] = __builtin_amdgcn_mfma_f32_16x16x32_f16(af[i], bf[j], acc[i][j], 0, 0, 0);
        if (c < 7) {
            #pragma unroll
            for (int e = 0; e < 2; ++e) {
                int idx = tid + e * 256;
                int o = idx >> 2, q = idx & 3;
                *(f16x8*)(&s_b[b ^ 1][o * LDA + q * 8]) = nw[e];
            }
        }
        __syncthreads();
    }

    #pragma unroll
    for (int j = 0; j < 4; ++j) {
        int col = wc * 64 + j * 16 + l15;
        float bv = P1b[col];
        #pragma unroll
        for (int i = 0; i < 2; ++i) {
            int rowb = wr * 32 + i * 16 + lk * 4;
            #pragma unroll
            for (int v = 0; v < 4; ++v)
                s_cat[(rowb + v) * LDC + col] = (_Float16)fmaxf(acc[i][j][v] + bv, 0.f);
        }
    }
    #pragma unroll
    for (int e = 0; e < 2; ++e) {
        int idx = tid + e * 256;
        int o = idx >> 2, q = idx & 3;
        *(f16x8*)(&s_b[0][o * LDA + q * 8]) = *(const f16x8*)(P2wf + (size_t)o * D + q * 8);
    }
    __syncthreads();

    f32x4 acc2[2][4];
    #pragma unroll
    for (int i = 0; i < 2; ++i)
        #pragma unroll
        for (int j = 0; j < 4; ++j) acc2[i][j] = (f32x4){0.f, 0.f, 0.f, 0.f};

    for (int c = 0; c < 4; ++c) {
        int b = c & 1;
        f16x8 nw[2];
        if (c < 3) {
            #pragma unroll
            for (int e = 0; e < 2; ++e) {
                int idx = tid + e * 256;
                int o = idx >> 2, q = idx & 3;
                nw[e] = *(const f16x8*)(P2wf + (size_t)o * D + (c + 1) * 32 + q * 8);
            }
        }
        f16x8 af[2], bf[4];
        af[0] = *(const f16x8*)(s_cat + (wr * 32 + l15) * LDC + c * 32 + lk * 8);
        af[1] = *(const f16x8*)(s_cat + (wr * 32 + 16 + l15) * LDC + c * 32 + lk * 8);
        #pragma unroll
        for (int j = 0; j < 4; ++j)
            bf[j] = *(const f16x8*)(&s_b[b][(wc * 64 + j * 16 + l15) * LDA + lk * 8]);
        #pragma unroll
        for (int i = 0; i < 2; ++i)
            #pragma unroll
            for (int j = 0; j < 4; ++j)
                acc2[i][j] = __builtin_amdgcn_mfma_f32_16x16x32_f16(af[i], bf[j], acc2[i][j], 0, 0, 0);
        if (c < 3) {
            #pragma unroll
            for (int e = 0; e < 2; ++e) {
                int idx = tid + e * 256;
                int o = idx >> 2, q = idx & 3;
                *(f16x8*)(&s_b[b ^ 1][o * LDA + q * 8]) = nw[e];
            }
        }
        __syncthreads();
    }

    float b2v[4], pw[4];
    #pragma unroll
    for (int j = 0; j < 4; ++j) {
        int col = wc * 64 + j * 16 + l15;
        b2v[j] = P2b[col];
        pw[j] = P3w[col];
    }
    #pragma unroll
    for (int i = 0; i < 2; ++i) {
        #pragma unroll
        for (int v = 0; v < 4; ++v) {
            float s = 0.f;
            #pragma unroll
            for (int j = 0; j < 4; ++j)
                s += fmaxf(acc2[i][j][v] + b2v[j], 0.f) * pw[j];
            s += __shfl_xor(s, 1);
            s += __shfl_xor(s, 2);
            s += __shfl_xor(s, 4);
            s += __shfl_xor(s, 8);
            if (l15 == 0)
                s_red[(wr * 32 + i * 16 + lk * 4 + v) * 2 + wc] = s;
        }
    }
    __syncthreads();
    if (tid < 64) {
        int p = p0 + tid;
        if (p < twoEP) out[p] = s_red[tid * 2] + s_red[tid * 2 + 1] + P3b[0];
    }
}

static inline size_t align_up(size_t x, size_t a) { return (x + a - 1) & ~(a - 1); }

extern "C" void kernel_launch(void* const* d_in, const int* in_sizes, int n_in,
                              void* d_out, int out_size, void* d_ws, size_t ws_size,
                              hipStream_t stream) {
    const float* x        = (const float*)d_in[0];
    const int*   edge_src = (const int*)d_in[1];
    const int*   edge_dst = (const int*)d_in[2];
    const int*   pos_src  = (const int*)d_in[3];
    const int*   pos_dst  = (const int*)d_in[4];
    const int*   neg_src  = (const int*)d_in[5];
    const int*   neg_dst  = (const int*)d_in[6];
    const float* W1n = (const float*)d_in[7];
    const float* W1s = (const float*)d_in[8];
    const float* b1  = (const float*)d_in[9];
    const float* W2n = (const float*)d_in[10];
    const float* W2s = (const float*)d_in[11];
    const float* b2  = (const float*)d_in[12];
    const float* P1w = (const float*)d_in[13];
    const float* P1b = (const float*)d_in[14];
    const float* P2w = (const float*)d_in[15];
    const float* P2b = (const float*)d_in[16];
    const float* P3w = (const float*)d_in[17];
    const float* P3b = (const float*)d_in[18];
    float* out = (float*)d_out;

    const int N = in_sizes[0] / D;
    const int E = in_sizes[1];
    const int EP = in_sizes[3];
    const int bound = (N + NR - 1) / NR;   // nodes per region (196 < 256)

    char* ws = (char*)d_ws;
    size_t off = 0;
    int* row_off = (int*)(ws + off); off = align_up(off + (size_t)(N + 1) * 4, 256);
    int* regmeta = (int*)(ws + off); off = align_up(off + (size_t)(3 * NR + 8) * 4, 256);
    int* csr     = (int*)(ws + off); off = align_up(off + (size_t)E * 4, 256);
    unsigned int* epart = (unsigned int*)(ws + off); off = align_up(off + (size_t)E * 4, 256);
    _Float16* xf   = (_Float16*)(ws + off); off = align_up(off + (size_t)N * D * 2, 256);
    _Float16* aggf = (_Float16*)(ws + off); off = align_up(off + (size_t)N * D * 2, 256);
    _Float16* h1f  = (_Float16*)(ws + off); off = align_up(off + (size_t)N * D * 2, 256);
    _Float16* h2f  = (_Float16*)(ws + off); off = align_up(off + (size_t)N * D * 2, 256);
    _Float16* Ws1f = (_Float16*)(ws + off); off = align_up(off + (size_t)D * D * 2, 256);
    _Float16* Wn1f = (_Float16*)(ws + off); off = align_up(off + (size_t)D * D * 2, 256);
    _Float16* Ws2f = (_Float16*)(ws + off); off = align_up(off + (size_t)D * D * 2, 256);
    _Float16* Wn2f = (_Float16*)(ws + off); off = align_up(off + (size_t)D * D * 2, 256);
    _Float16* P1wf = (_Float16*)(ws + off); off = align_up(off + (size_t)2 * D * D * 2, 256);
    _Float16* P2wf = (_Float16*)(ws + off); off = align_up(off + (size_t)D * D * 2, 256);
    (void)ws_size;

    int* region_cnt    = regmeta;               // [NR]
    int* region_base   = regmeta + NR;          // [NR+1]
    int* region_cursor = regmeta + 2 * NR + 4;  // [NR]

    // --- CSR build: histogram, base, partition, rowoff, scatter ---
    hipMemsetAsync(region_cnt, 0, NR * 4, stream);
    k_regcount<<<128, 256, 0, stream>>>(edge_dst, region_cnt, E, bound);
    k_regbase<<<1, 1, 0, stream>>>(region_cnt, region_base, region_cursor);
    k_regpart<<<(E + PART_CHUNK - 1) / PART_CHUNK, 256, 0, stream>>>(
        edge_src, edge_dst, epart, region_cursor, E, bound);
    k_rowoff<<<NR, 256, 0, stream>>>(epart, region_base, row_off, N, bound);
    k_scatter3<<<NR, 256, 0, stream>>>(epart, region_base, row_off, csr, N, bound);

    // --- f16 conversions ---
    k_cvt_f16<<<(N * D / 8 + 255) / 256, 256, 0, stream>>>(x, xf, N * D / 8);
    k_cvt_weights<<<56, 256, 0, stream>>>(W1s, W1n, W2s, W2n, P1w, P2w,
                                          Ws1f, Wn1f, Ws2f, Wn2f, P1wf, P2wf);

    const int ngrid = (N + 127) / 128;
    const int pgrid = (2 * EP + 63) / 64;

    // --- layer 1 ---
    k_agg<<<(N + 15) / 16, 256, 0, stream>>>(xf, row_off, csr, aggf, N);
    k_transform<<<ngrid, 512, 0, stream>>>(xf, aggf, Ws1f, Wn1f, b1, h1f, N, 1);
    // --- layer 2 ---
    k_agg<<<(N + 15) / 16, 256, 0, stream>>>(h1f, row_off, csr, aggf, N);
    k_transform<<<ngrid, 512, 0, stream>>>(h1f, aggf, Ws2f, Wn2f, b2, h2f, N, 0);

    // --- fused predictor ---
    k_mlp<<<pgrid, 256, 0, stream>>>(h2f, pos_src, pos_dst, neg_src, neg_dst,
                                     P1wf, P1b, P2wf, P2b, P3w, P3b, out, EP);
}

// Round 11
// 317.234 us; speedup vs baseline: 1.4130x; 1.0288x over previous
//
#include <hip/hip_runtime.h>
#include <hip/hip_bf16.h>
#include <hip/hip_fp16.h>

// GraphSAGE(2-layer, mean agg) + 3-layer MLP link predictor.
// N=100000, E=1.6M, E_PAIR=100000, D=128.
// Round 11: predictor P1 split by linearity — dense k_pre computes
// Pre[n] = [W1a@h2[n] | W1b@h2[n]] for all nodes; k_mlp gathers Pre rows,
// add+bias+relu, then P2/P3 only. LDS 55->39KB (2->4 blocks/CU).

#define D 128
#define NR 512
#define PART_CHUNK 4096
#define LDA 40       // f16 elems per staged row (80B stride: 2-way banks = free)
#define LDH2 136     // s_h1 row stride f16

typedef _Float16 f16x8 __attribute__((ext_vector_type(8)));
typedef float f32x4 __attribute__((ext_vector_type(4)));

// ---------------- phase 1: region histogram ----------------
__global__ __launch_bounds__(256) void k_regcount(
    const int* __restrict__ dst, int* __restrict__ region_cnt, int e, int bound) {
    __shared__ int s[NR];
    for (int i = threadIdx.x; i < NR; i += 256) s[i] = 0;
    __syncthreads();
    for (int i = blockIdx.x * 256 + threadIdx.x; i < e; i += gridDim.x * 256)
        atomicAdd(&s[dst[i] / bound], 1);
    __syncthreads();
    for (int i = threadIdx.x; i < NR; i += 256)
        if (s[i]) atomicAdd(&region_cnt[i], s[i]);
}

__global__ void k_regbase(const int* __restrict__ region_cnt,
                          int* __restrict__ region_base, int* __restrict__ region_cursor) {
    if (threadIdx.x == 0 && blockIdx.x == 0) {
        int run = 0;
        for (int r = 0; r < NR; ++r) {
            region_base[r] = run; region_cursor[r] = run; run += region_cnt[r];
        }
        region_base[NR] = run;
    }
}

// ---------------- phase 2: partition edges into region-compacted packed list ----------------
__global__ __launch_bounds__(256) void k_regpart(
    const int* __restrict__ src, const int* __restrict__ dst,
    unsigned int* __restrict__ eout, int* __restrict__ region_cursor, int e, int bound) {
    __shared__ int s_cnt[NR];
    __shared__ int s_base[NR];
    for (int c0 = blockIdx.x * PART_CHUNK; c0 < e; c0 += gridDim.x * PART_CHUNK) {
        int cend = min(c0 + PART_CHUNK, e);
        for (int i = threadIdx.x; i < NR; i += 256) s_cnt[i] = 0;
        __syncthreads();
        for (int i = c0 + threadIdx.x; i < cend; i += 256)
            atomicAdd(&s_cnt[dst[i] / bound], 1);
        __syncthreads();
        for (int i = threadIdx.x; i < NR; i += 256)
            s_base[i] = s_cnt[i] ? atomicAdd(&region_cursor[i], s_cnt[i]) : 0;
        __syncthreads();
        for (int i = threadIdx.x; i < NR; i += 256) s_cnt[i] = 0;
        __syncthreads();
        for (int i = c0 + threadIdx.x; i < cend; i += 256) {
            int d = dst[i];
            int r = d / bound;
            unsigned int doff = (unsigned int)(d - r * bound);
            int p = atomicAdd(&s_cnt[r], 1);
            eout[s_base[r] + p] = (unsigned int)src[i] | (doff << 20);
        }
        __syncthreads();
    }
}

// ---------------- phase 3a: per-region degree count + scan -> row_off ----------------
__global__ __launch_bounds__(256) void k_rowoff(
    const unsigned int* __restrict__ ep, const int* __restrict__ region_base,
    int* __restrict__ row_off, int n, int bound) {
    int r = blockIdx.x;
    int rlo = r * bound;
    if (threadIdx.x == 0 && r == 0) row_off[n] = region_base[NR];
    if (rlo >= n) return;
    int nn = min(bound, n - rlo);
    __shared__ int s_deg[256];
    __shared__ int s_scan[256];
    if (threadIdx.x < 256) s_deg[threadIdx.x] = 0;
    __syncthreads();
    int beg = region_base[r], end = region_base[r + 1];
    for (int i = beg + threadIdx.x; i < end; i += 256)
        atomicAdd(&s_deg[ep[i] >> 20], 1);
    __syncthreads();
    int v = (threadIdx.x < nn) ? s_deg[threadIdx.x] : 0;
    s_scan[threadIdx.x] = v;
    __syncthreads();
    #pragma unroll
    for (int off = 1; off < 256; off <<= 1) {
        int add = (threadIdx.x >= off) ? s_scan[threadIdx.x - off] : 0;
        __syncthreads();
        s_scan[threadIdx.x] += add;
        __syncthreads();
    }
    if (threadIdx.x < nn)
        row_off[rlo + threadIdx.x] = region_base[r] +
            (threadIdx.x ? s_scan[threadIdx.x - 1] : 0);
}

// ---------------- phase 3b: per-region scatter with LDS cursor ----------------
__global__ __launch_bounds__(256) void k_scatter3(
    const unsigned int* __restrict__ ep, const int* __restrict__ region_base,
    const int* __restrict__ row_off, int* __restrict__ csr, int n, int bound) {
    int r = blockIdx.x;
    int rlo = r * bound;
    if (rlo >= n) return;
    int nn = min(bound, n - rlo);
    __shared__ int s_cur[256];
    __shared__ int s_ro[256];
    if (threadIdx.x < nn) {
        s_cur[threadIdx.x] = 0;
        s_ro[threadIdx.x] = row_off[rlo + threadIdx.x];
    }
    __syncthreads();
    int beg = region_base[r], end = region_base[r + 1];
    for (int i = beg + threadIdx.x; i < end; i += 256) {
        unsigned int v = ep[i];
        int doff = v >> 20;
        int srcn = v & 0xFFFFF;
        int p = atomicAdd(&s_cur[doff], 1);
        csr[s_ro[doff] + p] = srcn;
    }
}

// ---------------- f32 -> f16 converts ----------------
__global__ void k_cvt_f16(const float* __restrict__ src, _Float16* __restrict__ dst, int n8) {
    int i = blockIdx.x * 256 + threadIdx.x;
    if (i >= n8) return;
    const float4* s4 = (const float4*)src;
    float4 a = s4[2 * i], b = s4[2 * i + 1];
    f16x8 h;
    h[0] = (_Float16)a.x; h[1] = (_Float16)a.y; h[2] = (_Float16)a.z; h[3] = (_Float16)a.w;
    h[4] = (_Float16)b.x; h[5] = (_Float16)b.y; h[6] = (_Float16)b.z; h[7] = (_Float16)b.w;
    *(f16x8*)(dst + 8 * i) = h;
}

// weights: W1s,W1n,W2s,W2n linear; P1w repacked to P1cf[256][128]
// (rows 0..127 = W1a = P1w[:, :128]; rows 128..255 = W1b = P1w[:, 128:]); P2w linear.
__global__ void k_cvt_weights(
    const float* __restrict__ W1s, const float* __restrict__ W1n,
    const float* __restrict__ W2s, const float* __restrict__ W2n,
    const float* __restrict__ P1w, const float* __restrict__ P2w,
    _Float16* __restrict__ Ws1f, _Float16* __restrict__ Wn1f,
    _Float16* __restrict__ Ws2f, _Float16* __restrict__ Wn2f,
    _Float16* __restrict__ P1cf, _Float16* __restrict__ P2wf) {
    int g = blockIdx.x * 256 + threadIdx.x;
    if (g >= 14336) return;
    const float* src; _Float16* dst; int off;
    if (g >= 8192 && g < 12288) {
        int u = g - 8192;
        int o = u >> 4, col = (u & 15) * 8;
        src = P1w + (size_t)(o & 127) * 256 + ((o >> 7) * 128) + col;
        float4 a = *(const float4*)src, b = *(const float4*)(src + 4);
        f16x8 h;
        h[0] = (_Float16)a.x; h[1] = (_Float16)a.y; h[2] = (_Float16)a.z; h[3] = (_Float16)a.w;
        h[4] = (_Float16)b.x; h[5] = (_Float16)b.y; h[6] = (_Float16)b.z; h[7] = (_Float16)b.w;
        *(f16x8*)(P1cf + (size_t)u * 8) = h;
        return;
    }
    if      (g <  2048) { src = W1s; dst = Ws1f; off = g; }
    else if (g <  4096) { src = W1n; dst = Wn1f; off = g - 2048; }
    else if (g <  6144) { src = W2s; dst = Ws2f; off = g - 4096; }
    else if (g <  8192) { src = W2n; dst = Wn2f; off = g - 6144; }
    else                { src = P2w; dst = P2wf; off = g - 12288; }
    const float4* s4 = (const float4*)src;
    float4 a = s4[2 * off], b = s4[2 * off + 1];
    f16x8 h;
    h[0] = (_Float16)a.x; h[1] = (_Float16)a.y; h[2] = (_Float16)a.z; h[3] = (_Float16)a.w;
    h[4] = (_Float16)b.x; h[5] = (_Float16)b.y; h[6] = (_Float16)b.z; h[7] = (_Float16)b.w;
    *(f16x8*)(dst + 8 * off) = h;
}

// ---------------- mean aggregation: 16-lane group per node, 4-deep ----------------
__global__ __launch_bounds__(256) void k_agg(
    const _Float16* __restrict__ Xf, const int* __restrict__ row_off,
    const int* __restrict__ csr, _Float16* __restrict__ Aggf, int n_nodes) {
    int g = blockIdx.x * 16 + (threadIdx.x >> 4);
    if (g >= n_nodes) return;
    int l = threadIdx.x & 15;
    int beg = row_off[g], end = row_off[g + 1];
    float acc[8] = {0.f, 0.f, 0.f, 0.f, 0.f, 0.f, 0.f, 0.f};
    int i = beg;
    for (; i + 4 <= end; i += 4) {
        int s0 = csr[i], s1 = csr[i + 1], s2 = csr[i + 2], s3 = csr[i + 3];
        f16x8 v0 = *(const f16x8*)(Xf + (size_t)s0 * D + l * 8);
        f16x8 v1 = *(const f16x8*)(Xf + (size_t)s1 * D + l * 8);
        f16x8 v2 = *(const f16x8*)(Xf + (size_t)s2 * D + l * 8);
        f16x8 v3 = *(const f16x8*)(Xf + (size_t)s3 * D + l * 8);
        #pragma unroll
        for (int j = 0; j < 8; ++j)
            acc[j] += ((float)v0[j] + (float)v1[j]) + ((float)v2[j] + (float)v3[j]);
    }
    for (; i < end; ++i) {
        int s0 = csr[i];
        f16x8 v0 = *(const f16x8*)(Xf + (size_t)s0 * D + l * 8);
        #pragma unroll
        for (int j = 0; j < 8; ++j) acc[j] += (float)v0[j];
    }
    float inv = 1.0f / fmaxf((float)(end - beg), 1.0f);
    f16x8 o;
    #pragma unroll
    for (int j = 0; j < 8; ++j) o[j] = (_Float16)(acc[j] * inv);
    *(f16x8*)(Aggf + (size_t)g * D + l * 8) = o;
}

// ---------------- layer transform (MFMA, double-buffered) ----------------
__global__ __launch_bounds__(512) void k_transform(
    const _Float16* __restrict__ Xf, const _Float16* __restrict__ Aggf,
    const _Float16* __restrict__ Wsf, const _Float16* __restrict__ Wnf,
    const float* __restrict__ bias, _Float16* __restrict__ outf,
    int n_rows, int do_relu) {
    __shared__ _Float16 s_a[2][128 * LDA];
    __shared__ _Float16 s_b[2][128 * LDA];
    int tid = threadIdx.x;
    int w = tid >> 6, l = tid & 63;
    int wr = w >> 1, wc = w & 1;
    int l15 = l & 15, lk = l >> 4;
    int n0 = blockIdx.x * 128;
    int r = tid >> 2, q = tid & 3;
    int rstage = n0 + r; if (rstage >= n_rows) rstage = n_rows - 1;

    f32x4 acc[2][4];
    #pragma unroll
    for (int i = 0; i < 2; ++i)
        #pragma unroll
        for (int j = 0; j < 4; ++j) acc[i][j] = (f32x4){0.f, 0.f, 0.f, 0.f};

    int a_off = (wr * 32 + l15) * LDA + lk * 8;
    int b_off = (wc * 64 + l15) * LDA + lk * 8;
    int st_off = r * LDA + q * 8;

    {
        f16x8 av = *(const f16x8*)(Xf + (size_t)rstage * D + q * 8);
        f16x8 wv = *(const f16x8*)(Wsf + (size_t)r * D + q * 8);
        *(f16x8*)(&s_a[0][st_off]) = av;
        *(f16x8*)(&s_b[0][st_off]) = wv;
    }
    __syncthreads();

    for (int c = 0; c < 8; ++c) {
        int b = c & 1;
        f16x8 av, wv;
        if (c < 7) {
            int cn = c + 1;
            const _Float16* asrc = (cn < 4) ? Xf : Aggf;
            const _Float16* wsrc = (cn < 4) ? Wsf : Wnf;
            int kb = (cn & 3) * 32;
            av = *(const f16x8*)(asrc + (size_t)rstage * D + kb + q * 8);
            wv = *(const f16x8*)(wsrc + (size_t)r * D + kb + q * 8);
        }
        f16x8 af[2], bf[4];
        af[0] = *(const f16x8*)(&s_a[b][a_off]);
        af[1] = *(const f16x8*)(&s_a[b][a_off + 16 * LDA]);
        #pragma unroll
        for (int j = 0; j < 4; ++j) bf[j] = *(const f16x8*)(&s_b[b][b_off + j * 16 * LDA]);
        #pragma unroll
        for (int i = 0; i < 2; ++i)
            #pragma unroll
            for (int j = 0; j < 4; ++j)
                acc[i][j] = __builtin_amdgcn_mfma_f32_16x16x32_f16(af[i], bf[j], acc[i][j], 0, 0, 0);
        if (c < 7) {
            *(f16x8*)(&s_a[b ^ 1][st_off]) = av;
            *(f16x8*)(&s_b[b ^ 1][st_off]) = wv;
        }
        __syncthreads();
    }

    #pragma unroll
    for (int j = 0; j < 4; ++j) {
        int col = wc * 64 + j * 16 + l15;
        float bv = bias[col];
        #pragma unroll
        for (int i = 0; i < 2; ++i) {
            int rowb = n0 + wr * 32 + i * 16 + lk * 4;
            #pragma unroll
            for (int v = 0; v < 4; ++v) {
                int row = rowb + v;
                if (row < n_rows) {
                    float xv = acc[i][j][v] + bv;
                    if (do_relu) xv = fmaxf(xv, 0.f);
                    outf[(size_t)row * D + col] = (_Float16)xv;
                }
            }
        }
    }
}

// ---------------- k_pre: Pre[n][o] = sum_k h2[n][k] * P1cf[o][k], o in [0,256) ----------------
// 512 thr = 8 waves; block tile 64 rows x 256 cols; wave (wr=w>>2, wc=w&3).
__global__ __launch_bounds__(512) void k_pre(
    const _Float16* __restrict__ Hf, const _Float16* __restrict__ P1cf,
    _Float16* __restrict__ Pre, int n_rows) {
    __shared__ _Float16 s_a[64 * LDA];
    __shared__ _Float16 s_b[256 * LDA];
    int tid = threadIdx.x;
    int w = tid >> 6, l = tid & 63;
    int wr = w >> 2, wc = w & 3;
    int l15 = l & 15, lk = l >> 4;
    int n0 = blockIdx.x * 64;

    f32x4 acc[2][4];
    #pragma unroll
    for (int i = 0; i < 2; ++i)
        #pragma unroll
        for (int j = 0; j < 4; ++j) acc[i][j] = (f32x4){0.f, 0.f, 0.f, 0.f};

    int a_off = (wr * 32 + l15) * LDA + lk * 8;

    for (int c = 0; c < 4; ++c) {
        int kb = c * 32;
        __syncthreads();
        if (tid < 256) {
            int r = tid >> 2, q = tid & 3;
            int rstage = n0 + r; if (rstage >= n_rows) rstage = n_rows - 1;
            *(f16x8*)(&s_a[r * LDA + q * 8]) =
                *(const f16x8*)(Hf + (size_t)rstage * D + kb + q * 8);
        }
        #pragma unroll
        for (int e = 0; e < 2; ++e) {
            int idx = tid + e * 512;
            int o = idx >> 2, q = idx & 3;
            *(f16x8*)(&s_b[o * LDA + q * 8]) =
                *(const f16x8*)(P1cf + (size_t)o * 128 + kb + q * 8);
        }
        __syncthreads();
        f16x8 af[2], bf[4];
        af[0] = *(const f16x8*)(&s_a[a_off]);
        af[1] = *(const f16x8*)(&s_a[a_off + 16 * LDA]);
        #pragma unroll
        for (int j = 0; j < 4; ++j)
            bf[j] = *(const f16x8*)(&s_b[(wc * 64 + j * 16 + l15) * LDA + lk * 8]);
        #pragma unroll
        for (int i = 0; i < 2; ++i)
            #pragma unroll
            for (int j = 0; j < 4; ++j)
                acc[i][j] = __builtin_amdgcn_mfma_f32_16x16x32_f16(af[i], bf[j], acc[i][j], 0, 0, 0);
    }

    #pragma unroll
    for (int j = 0; j < 4; ++j) {
        int col = wc * 64 + j * 16 + l15;
        #pragma unroll
        for (int i = 0; i < 2; ++i) {
            int rowb = n0 + wr * 32 + i * 16 + lk * 4;
            #pragma unroll
            for (int v = 0; v < 4; ++v) {
                int row = rowb + v;
                if (row < n_rows)
                    Pre[(size_t)row * 256 + col] = (_Float16)acc[i][j][v];
            }
        }
    }
}

// ---------------- fused predictor: gather Pre rows -> h1 -> P2 -> P3 ----------------
__global__ __launch_bounds__(256) void k_mlp(
    const _Float16* __restrict__ Pre,
    const int* __restrict__ pos_src, const int* __restrict__ pos_dst,
    const int* __restrict__ neg_src, const int* __restrict__ neg_dst,
    const float* __restrict__ P1b,
    const _Float16* __restrict__ P2wf, const float* __restrict__ P2b,
    const float* __restrict__ P3w, const float* __restrict__ P3b,
    float* __restrict__ out, int EP) {
    __shared__ _Float16 s_h1[64 * LDH2];
    __shared__ _Float16 s_b[2][128 * LDA];
    __shared__ float s_red[64 * 2];
    __shared__ int s_node[128];
    int tid = threadIdx.x;
    int w = tid >> 6, l = tid & 63;
    int wr = w >> 1, wc = w & 1;
    int l15 = l & 15, lk = l >> 4;
    int p0 = blockIdx.x * 64;
    int twoEP = 2 * EP;

    if (tid < 128) {
        int p = p0 + (tid & 63);
        if (p >= twoEP) p = twoEP - 1;
        int node;
        if (tid < 64) node = (p < EP) ? pos_src[p] : neg_src[p - EP];
        else          node = (p < EP) ? pos_dst[p] : neg_dst[p - EP];
        s_node[tid] = node;
    }
    __syncthreads();

    // gather + combine: h1[pr][u*8..] = relu(Pre[src][u*8..] + Pre[dst][128+u*8..] + P1b)
    #pragma unroll
    for (int e = 0; e < 4; ++e) {
        int idx = tid + e * 256;         // [0,1024): pr = idx>>4, u = idx&15
        int pr = idx >> 4, u = idx & 15;
        int sn = s_node[pr], dn = s_node[64 + pr];
        f16x8 a = *(const f16x8*)(Pre + (size_t)sn * 256 + u * 8);
        f16x8 b = *(const f16x8*)(Pre + (size_t)dn * 256 + 128 + u * 8);
        float4 b0 = *(const float4*)(P1b + u * 8);
        float4 b1 = *(const float4*)(P1b + u * 8 + 4);
        float bb[8] = {b0.x, b0.y, b0.z, b0.w, b1.x, b1.y, b1.z, b1.w};
        f16x8 h;
        #pragma unroll
        for (int j = 0; j < 8; ++j)
            h[j] = (_Float16)fmaxf((float)a[j] + (float)b[j] + bb[j], 0.f);
        *(f16x8*)(&s_h1[pr * LDH2 + u * 8]) = h;
    }
    // stage P2 chunk 0
    #pragma unroll
    for (int e = 0; e < 2; ++e) {
        int idx = tid + e * 256;
        int o = idx >> 2, q = idx & 3;
        *(f16x8*)(&s_b[0][o * LDA + q * 8]) = *(const f16x8*)(P2wf + (size_t)o * D + q * 8);
    }
    __syncthreads();

    // ---- P2: [64 x 128] @ W2^T, 4 chunks, dbuf ----
    f32x4 acc2[2][4];
    #pragma unroll
    for (int i = 0; i < 2; ++i)
        #pragma unroll
        for (int j = 0; j < 4; ++j) acc2[i][j] = (f32x4){0.f, 0.f, 0.f, 0.f};

    for (int c = 0; c < 4; ++c) {
        int b = c & 1;
        f16x8 nw[2];
        if (c < 3) {
            #pragma unroll
            for (int e = 0; e < 2; ++e) {
                int idx = tid + e * 256;
                int o = idx >> 2, q = idx & 3;
                nw[e] = *(const f16x8*)(P2wf + (size_t)o * D + (c + 1) * 32 + q * 8);
            }
        }
        f16x8 af[2], bf[4];
        af[0] = *(const f16x8*)(&s_h1[(wr * 32 + l15) * LDH2 + c * 32 + lk * 8]);
        af[1] = *(const f16x8*)(&s_h1[(wr * 32 + 16 + l15) * LDH2 + c * 32 + lk * 8]);
        #pragma unroll
        for (int j = 0; j < 4; ++j)
            bf[j] = *(const f16x8*)(&s_b[b][(wc * 64 + j * 16 + l15) * LDA + lk * 8]);
        #pragma unroll
        for (int i = 0; i < 2; ++i)
            #pragma unroll
            for (int j = 0; j < 4; ++j)
                acc2[i][j] = __builtin_amdgcn_mfma_f32_16x16x32_f16(af[i], bf[j], acc2[i][j], 0, 0, 0);
        if (c < 3) {
            #pragma unroll
            for (int e = 0; e < 2; ++e) {
                int idx = tid + e * 256;
                int o = idx >> 2, q = idx & 3;
                *(f16x8*)(&s_b[b ^ 1][o * LDA + q * 8]) = nw[e];
            }
        }
        __syncthreads();
    }

    // ---- P3 ----
    float b2v[4], pw[4];
    #pragma unroll
    for (int j = 0; j < 4; ++j) {
        int col = wc * 64 + j * 16 + l15;
        b2v[j] = P2b[col];
        pw[j] = P3w[col];
    }
    #pragma unroll
    for (int i = 0; i < 2; ++i) {
        #pragma unroll
        for (int v = 0; v < 4; ++v) {
            float s = 0.f;
            #pragma unroll
            for (int j = 0; j < 4; ++j)
                s += fmaxf(acc2[i][j][v] + b2v[j], 0.f) * pw[j];
            s += __shfl_xor(s, 1);
            s += __shfl_xor(s, 2);
            s += __shfl_xor(s, 4);
            s += __shfl_xor(s, 8);
            if (l15 == 0)
                s_red[(wr * 32 + i * 16 + lk * 4 + v) * 2 + wc] = s;
        }
    }
    __syncthreads();
    if (tid < 64) {
        int p = p0 + tid;
        if (p < twoEP) out[p] = s_red[tid * 2] + s_red[tid * 2 + 1] + P3b[0];
    }
}

static inline size_t align_up(size_t x, size_t a) { return (x + a - 1) & ~(a - 1); }

extern "C" void kernel_launch(void* const* d_in, const int* in_sizes, int n_in,
                              void* d_out, int out_size, void* d_ws, size_t ws_size,
                              hipStream_t stream) {
    const float* x        = (const float*)d_in[0];
    const int*   edge_src = (const int*)d_in[1];
    const int*   edge_dst = (const int*)d_in[2];
    const int*   pos_src  = (const int*)d_in[3];
    const int*   pos_dst  = (const int*)d_in[4];
    const int*   neg_src  = (const int*)d_in[5];
    const int*   neg_dst  = (const int*)d_in[6];
    const float* W1n = (const float*)d_in[7];
    const float* W1s = (const float*)d_in[8];
    const float* b1  = (const float*)d_in[9];
    const float* W2n = (const float*)d_in[10];
    const float* W2s = (const float*)d_in[11];
    const float* b2  = (const float*)d_in[12];
    const float* P1w = (const float*)d_in[13];
    const float* P1b = (const float*)d_in[14];
    const float* P2w = (const float*)d_in[15];
    const float* P2b = (const float*)d_in[16];
    const float* P3w = (const float*)d_in[17];
    const float* P3b = (const float*)d_in[18];
    float* out = (float*)d_out;

    const int N = in_sizes[0] / D;
    const int E = in_sizes[1];
    const int EP = in_sizes[3];
    const int bound = (N + NR - 1) / NR;   // nodes per region (196 < 256)

    char* ws = (char*)d_ws;
    size_t off = 0;
    int* row_off = (int*)(ws + off); off = align_up(off + (size_t)(N + 1) * 4, 256);
    int* regmeta = (int*)(ws + off); off = align_up(off + (size_t)(3 * NR + 8) * 4, 256);
    int* csr     = (int*)(ws + off); off = align_up(off + (size_t)E * 4, 256);
    unsigned int* epart = (unsigned int*)(ws + off); off = align_up(off + (size_t)E * 4, 256);
    _Float16* xf   = (_Float16*)(ws + off); off = align_up(off + (size_t)N * D * 2, 256);
    _Float16* aggf = (_Float16*)(ws + off); off = align_up(off + (size_t)N * D * 2, 256);
    _Float16* h1f  = (_Float16*)(ws + off); off = align_up(off + (size_t)N * D * 2, 256);
    _Float16* h2f  = (_Float16*)(ws + off); off = align_up(off + (size_t)N * D * 2, 256);
    _Float16* Ws1f = (_Float16*)(ws + off); off = align_up(off + (size_t)D * D * 2, 256);
    _Float16* Wn1f = (_Float16*)(ws + off); off = align_up(off + (size_t)D * D * 2, 256);
    _Float16* Ws2f = (_Float16*)(ws + off); off = align_up(off + (size_t)D * D * 2, 256);
    _Float16* Wn2f = (_Float16*)(ws + off); off = align_up(off + (size_t)D * D * 2, 256);
    _Float16* P1cf = (_Float16*)(ws + off); off = align_up(off + (size_t)2 * D * D * 2, 256);
    _Float16* P2wf = (_Float16*)(ws + off); off = align_up(off + (size_t)D * D * 2, 256);
    (void)ws_size;

    // Pre[N][256] aliases xf+aggf (both dead after transform2; 2 x 25.6MB = 51.2MB)
    _Float16* Pre = xf;

    int* region_cnt    = regmeta;               // [NR]
    int* region_base   = regmeta + NR;          // [NR+1]
    int* region_cursor = regmeta + 2 * NR + 4;  // [NR]

    // --- CSR build: histogram, base, partition, rowoff, scatter ---
    hipMemsetAsync(region_cnt, 0, NR * 4, stream);
    k_regcount<<<128, 256, 0, stream>>>(edge_dst, region_cnt, E, bound);
    k_regbase<<<1, 1, 0, stream>>>(region_cnt, region_base, region_cursor);
    k_regpart<<<(E + PART_CHUNK - 1) / PART_CHUNK, 256, 0, stream>>>(
        edge_src, edge_dst, epart, region_cursor, E, bound);
    k_rowoff<<<NR, 256, 0, stream>>>(epart, region_base, row_off, N, bound);
    k_scatter3<<<NR, 256, 0, stream>>>(epart, region_base, row_off, csr, N, bound);

    // --- f16 conversions ---
    k_cvt_f16<<<(N * D / 8 + 255) / 256, 256, 0, stream>>>(x, xf, N * D / 8);
    k_cvt_weights<<<56, 256, 0, stream>>>(W1s, W1n, W2s, W2n, P1w, P2w,
                                          Ws1f, Wn1f, Ws2f, Wn2f, P1cf, P2wf);

    const int ngrid = (N + 127) / 128;
    const int pgrid = (2 * EP + 63) / 64;

    // --- layer 1 ---
    k_agg<<<(N + 15) / 16, 256, 0, stream>>>(xf, row_off, csr, aggf, N);
    k_transform<<<ngrid, 512, 0, stream>>>(xf, aggf, Ws1f, Wn1f, b1, h1f, N, 1);
    // --- layer 2 ---
    k_agg<<<(N + 15) / 16, 256, 0, stream>>>(h1f, row_off, csr, aggf, N);
    k_transform<<<ngrid, 512, 0, stream>>>(h1f, aggf, Ws2f, Wn2f, b2, h2f, N, 0);

    // --- predictor: dense P1 halves then pair gather + P2/P3 ---
    k_pre<<<(N + 63) / 64, 512, 0, stream>>>(h2f, P1cf, Pre, N);
    k_mlp<<<pgrid, 256, 0, stream>>>(Pre, pos_src, pos_dst, neg_src, neg_dst,
                                     P1b, P2wf, P2b, P3w, P3b, out, EP);
}